// Round 3
// baseline (237.326 us; speedup 1.0000x reference)
//
#include <hip/hip_runtime.h>
#include <math.h>

// Problem constants (match reference)
#define NROWS 65536          // B*S = 16*4096
#define CIN   768
#define QCOUNT 524288.0      // NROWS * DDIM
#define RPW   16             // rows per wave (amortizes Wc-in-registers)
#define NBLK  (NROWS / (4 * RPW))   // 1024 blocks of 4 waves

// One wave processes RPW rows, one row at a time, A/B software pipeline.
// Lane mapping: dg = lane&7 (quantizer dim), lev = lane>>3 (codebook level).
// Wc (24KB) lives in per-lane registers (96 VGPR), filled once via LDS.
// We (24KB) lives in LDS, read per row with conflict-free consecutive-lane b128.

// Distributing butterfly: reduce 8 per-lane f64 partials across 64 lanes,
// delivering zc[d] to lanes with (lane&7)==d. Fixed order, static selects.
#define REDUCE_TO_MINE(da, out)                                            \
    {                                                                      \
        double k0 = b0 ? da[1] : da[0], s0 = b0 ? da[0] : da[1];           \
        double k1 = b0 ? da[3] : da[2], s1 = b0 ? da[2] : da[3];           \
        double k2 = b0 ? da[5] : da[4], s2 = b0 ? da[4] : da[5];           \
        double k3 = b0 ? da[7] : da[6], s3 = b0 ? da[6] : da[7];           \
        k0 += __shfl_xor(s0, 1); k1 += __shfl_xor(s1, 1);                  \
        k2 += __shfl_xor(s2, 1); k3 += __shfl_xor(s3, 1);                  \
        double m0 = b1 ? k1 : k0, t0 = b1 ? k0 : k1;                       \
        double m1 = b1 ? k3 : k2, t1 = b1 ? k2 : k3;                       \
        m0 += __shfl_xor(t0, 2); m1 += __shfl_xor(t1, 2);                  \
        double r = b2 ? m1 : m0, tq = b2 ? m0 : m1;                        \
        r += __shfl_xor(tq, 4);                                            \
        r += __shfl_xor(r, 8);                                             \
        r += __shfl_xor(r, 16);                                            \
        r += __shfl_xor(r, 32);                                            \
        out = r;                                                           \
    }

// Load one row's z (3 coalesced float4) + u (coalesced permuted 256B)
#define LOADZ(B, row)                                                      \
    B##0 = z4[(size_t)(row) * 192 + lane];                                 \
    B##1 = z4[(size_t)(row) * 192 + lane + 64];                           \
    B##2 = z4[(size_t)(row) * 192 + lane + 128];                          \
    B##u = u[(size_t)(row) * 64 + dg * 8 + lev];

// compress: zc = z @ Wc (+bc). f32 FMA within 4-chunk, f64 chunk accum —
// EXACT same arithmetic order as the verified absmax-0.0 kernel.
#define COMPRESS(B, ZCOUT)                                                 \
    {                                                                      \
        double da[8];                                                      \
        _Pragma("unroll") for (int d = 0; d < 8; ++d) da[d] = 0.0;         \
        _Pragma("unroll") for (int j = 0; j < 3; ++j) {                    \
            const float4 zv = (j == 0) ? B##0 : (j == 1) ? B##1 : B##2;    \
            float f[8];                                                    \
            _Pragma("unroll") for (int d = 0; d < 8; ++d) f[d] = 0.f;      \
            _Pragma("unroll") for (int k = 0; k < 4; ++k) {                \
                const float a = (k==0)?zv.x:(k==1)?zv.y:(k==2)?zv.z:zv.w;  \
                const float4 wA = wcA[j][k];                               \
                const float4 wB = wcB[j][k];                               \
                f[0]=fmaf(a,wA.x,f[0]); f[1]=fmaf(a,wA.y,f[1]);            \
                f[2]=fmaf(a,wA.z,f[2]); f[3]=fmaf(a,wA.w,f[3]);            \
                f[4]=fmaf(a,wB.x,f[4]); f[5]=fmaf(a,wB.y,f[5]);            \
                f[6]=fmaf(a,wB.z,f[6]); f[7]=fmaf(a,wB.w,f[7]);            \
            }                                                              \
            _Pragma("unroll") for (int d = 0; d < 8; ++d)                  \
                da[d] += (double)f[d];                                     \
        }                                                                  \
        REDUCE_TO_MINE(da, ZCOUT)                                         \
        ZCOUT += bc_mine;                                                  \
    }

// gumbel + argmax + qerr-accumulate + expand + store for one row
#define FINISH(row, ZC, UVF)                                               \
    {                                                                      \
        const double uv = (double)(UVF) + 1e-10;                           \
        const double g  = -log(-log(uv));                                  \
        double n  = g - fabs(ZC - (double)cb_mine);   /* TAU = 1 */        \
        int    li = lev;                                                   \
        float  ci = cb_mine;                                               \
        _Pragma("unroll") for (int s = 8; s <= 32; s <<= 1) {              \
            const double on = __shfl_xor(n, s);                            \
            const int    ol = __shfl_xor(li, s);                           \
            const float  oc = __shfl_xor(ci, s);                           \
            const bool   t  = (on > n) || (on == n && ol < li);            \
            n = t ? on : n; li = t ? ol : li; ci = t ? oc : ci;            \
        }                                                                  \
        const double e = ZC - (double)ci;                                  \
        qa += e * e;                                                       \
        float code[8];                                                     \
        _Pragma("unroll") for (int d = 0; d < 8; ++d)                      \
            code[d] = __shfl(ci, (lane & 56) | d);                         \
        _Pragma("unroll") for (int j = 0; j < 3; ++j) {                    \
            const int fi = lane + 64 * j;                                  \
            float4 o = beR[j];                                             \
            _Pragma("unroll") for (int d = 0; d < 8; ++d) {                \
                const float4 wv = lds_w[1536 + d * 192 + fi];              \
                o.x = fmaf(code[d], wv.x, o.x);                            \
                o.y = fmaf(code[d], wv.y, o.y);                            \
                o.z = fmaf(code[d], wv.z, o.z);                            \
                o.w = fmaf(code[d], wv.w, o.w);                            \
            }                                                              \
            zq4[(size_t)(row) * 192 + fi] = o;                             \
        }                                                                  \
    }

template <int USE_BPART>
__global__ __launch_bounds__(256, 2) void fsq_main(
    const float* __restrict__ z, const float* __restrict__ u,
    const float* __restrict__ Wc, const float* __restrict__ bc,
    const float* __restrict__ We, const float* __restrict__ be,
    const float* __restrict__ cb, float* __restrict__ zq,
    double* __restrict__ bpart)
{
    __shared__ float4 lds_w[3072];   // [0,1536): Wc,  [1536,3072): We
    __shared__ double wsum[4];

    const int lane = threadIdx.x & 63;
    const int wid  = threadIdx.x >> 6;
    const int dg   = lane & 7;
    const int lev  = lane >> 3;

    // ---- block setup: stage Wc + We into LDS, coalesced, once ----
    {
        const float4* __restrict__ Wc4 = (const float4*)Wc;
        const float4* __restrict__ We4 = (const float4*)We;
        for (int t = threadIdx.x; t < 1536; t += 256) lds_w[t] = Wc4[t];
        for (int t = threadIdx.x; t < 1536; t += 256) lds_w[1536 + t] = We4[t];
    }
    __syncthreads();

    // ---- one-time per-lane register fills ----
    // Wc rows 4*fi .. 4*fi+3 (fi = lane+64j) -> 24 float4 = 96 VGPR.
    float4 wcA[3][4], wcB[3][4];
#pragma unroll
    for (int j = 0; j < 3; ++j) {
        const int fi = lane + 64 * j;
#pragma unroll
        for (int k = 0; k < 4; ++k) {
            const int c = fi * 4 + k;        // Wc row index
            wcA[j][k] = lds_w[2 * c];        // d = 0..3
            wcB[j][k] = lds_w[2 * c + 1];    // d = 4..7
        }
    }
    float4 beR[3];
    {
        const float4* __restrict__ be4 = (const float4*)be;
#pragma unroll
        for (int j = 0; j < 3; ++j) beR[j] = be4[lane + 64 * j];
    }
    const float  cb_mine = cb[dg * 8 + lev];
    const double bc_mine = (double)bc[dg];
    const int b0 = lane & 1, b1 = (lane >> 1) & 1, b2 = (lane >> 2) & 1;

    const float4* __restrict__ z4 = (const float4*)z;
    float4* __restrict__ zq4 = (float4*)zq;

    const int wbase = (blockIdx.x * 4 + wid) * RPW;
    double qa = 0.0;

    // ---- row loop: 2 rows per trip, A/B software pipeline ----
    float4 zA0, zA1, zA2, zB0, zB1, zB2;
    float  zAu, zBu;
    double zcA, zcB;
    LOADZ(zA, wbase)
#pragma unroll 1
    for (int itp = 0; itp < RPW / 2; ++itp) {
        const int r0 = wbase + 2 * itp;
        COMPRESS(zA, zcA)
        const float uvA = zAu;
        LOADZ(zB, r0 + 1)                 // prefetch row r0+1 under FINISH(A)
        FINISH(r0, zcA, uvA)
        COMPRESS(zB, zcB)
        const float uvB = zBu;
        if (itp != RPW / 2 - 1) { LOADZ(zA, r0 + 2) }  // prefetch next trip
        FINISH(r0 + 1, zcB, uvB)
    }

    // ---- quantization error: dg-reduce once per wave ----
    // qa holds sum over this lane's dg across RPW rows (replicated over lev
    // groups); xor 1/2/4 sums dg 0..7 within each 8-lane group.
    qa += __shfl_xor(qa, 1);
    qa += __shfl_xor(qa, 2);
    qa += __shfl_xor(qa, 4);
    if (USE_BPART) {
        if (lane == 0) wsum[wid] = qa;
        __syncthreads();
        if (threadIdx.x == 0)
            bpart[blockIdx.x] = (wsum[0] + wsum[1]) + (wsum[2] + wsum[3]);
    } else {
        if (lane == 0) atomicAdd(bpart, qa);
    }
}

// Deterministic fixed-order reduction of NBLK partials -> mean -> out.
__global__ __launch_bounds__(256) void fsq_tail_bpart(
    const double* __restrict__ bpart, float* __restrict__ out)
{
    __shared__ double s[256];
    const int t = threadIdx.x;
    double a = 0.0;
    for (int i = 0; i < NBLK / 256; ++i)          // fixed order
        a += bpart[t * (NBLK / 256) + i];
    s[t] = a;
    __syncthreads();
    for (int w = 128; w > 0; w >>= 1) {
        if (t < w) s[t] += s[t + w];
        __syncthreads();
    }
    if (t == 0) out[0] = (float)(s[0] * (1.0 / QCOUNT));
}

__global__ void fsq_tail_atomic(const double* __restrict__ qacc, float* __restrict__ out)
{
    out[0] = (float)(qacc[0] * (1.0 / QCOUNT));
}

extern "C" void kernel_launch(void* const* d_in, const int* in_sizes, int n_in,
                              void* d_out, int out_size, void* d_ws, size_t ws_size,
                              hipStream_t stream)
{
    const float* z  = (const float*)d_in[0];
    const float* u  = (const float*)d_in[1];
    const float* Wc = (const float*)d_in[2];
    const float* bc = (const float*)d_in[3];
    const float* We = (const float*)d_in[4];
    const float* be = (const float*)d_in[5];
    const float* cb = (const float*)d_in[6];
    // d_in[7] = codebook_mask: all levels == 8 -> mask all true, unused.

    float*  zq    = (float*)d_out;
    double* bpart = (double*)d_ws;

    if (ws_size >= (size_t)NBLK * sizeof(double)) {
        // no memset needed: every block overwrites its own slot
        fsq_main<1><<<dim3(NBLK), dim3(256), 0, stream>>>(z, u, Wc, bc, We, be, cb, zq, bpart);
        fsq_tail_bpart<<<dim3(1), dim3(256), 0, stream>>>(bpart, zq + (size_t)NROWS * CIN);
    } else {
        hipMemsetAsync(d_ws, 0, sizeof(double), stream);
        fsq_main<0><<<dim3(NBLK), dim3(256), 0, stream>>>(z, u, Wc, bc, We, be, cb, zq, bpart);
        fsq_tail_atomic<<<dim3(1), dim3(1), 0, stream>>>(bpart, zq + (size_t)NROWS * CIN);
    }
}